// Round 7
// baseline (329.395 us; speedup 1.0000x reference)
//
#include <hip/hip_runtime.h>

namespace {

typedef __bf16 bf16x8 __attribute__((ext_vector_type(8)));
typedef float f32x4 __attribute__((ext_vector_type(4)));

constexpr int NB = 6;          // batches per block
constexpr int ROWS = 60;       // NB * T   (row = t*6 + b)
constexpr int MT = 4;          // M-tiles of 16 (rows 60..63 are masked garbage)
constexpr int APAD = 72;       // bf16 staging row pitch (144 B, 16B-aligned)
constexpr int TPITCH = 62;     // V^T pitch (124 B = 31 words, odd -> conflict-free)
constexpr int PPITCH = 12;     // P row pitch (24 B, 8B-aligned rows)
constexpr int NBLK = (16384 + NB - 1) / NB;  // 2731 (tail block partial)
constexpr float EPS = 1e-5f;

// ws bf16-fragment offsets (elements)
constexpr int PROJF_OFF = 36864;
constexpr int F1F_OFF = 49152;
constexpr int F2F_OFF = 98304;
constexpr int WS_ELEMS = 147456;

// LDS arena offsets (bytes)
constexpr int ACT_OFF = 0;           // bf16[60][72] 8640  (aliased: bufT bf16[64][62]=7936)
constexpr int BUFQ_OFF = 8640;       // bf16[60][72] 8640  (hscr f32[64][66]=16896 spans Q+K)
constexpr int BUFK_OFF = 17280;      // bf16[60][72] 8640  (also y destination)
constexpr int SPR_OFF = 25920;       // 5760: sP bf16[24*10*12] | sXf f32[240] | sPart+sGB
constexpr int ARENA_BYTES = 31680;   // 163840/31680 -> 5 blocks/CU

__device__ __forceinline__ uint pk2(float lo, float hi) {
  ushort ul = __builtin_bit_cast(ushort, (__bf16)lo);
  ushort uh = __builtin_bit_cast(ushort, (__bf16)hi);
  return (uint)ul | ((uint)uh << 16);
}
__device__ __forceinline__ float blo(uint u) { return __uint_as_float(u << 16); }
__device__ __forceinline__ float bhi(uint u) { return __uint_as_float(u & 0xffff0000u); }
__device__ __forceinline__ void unpack8(int4 v, float* f) {
  f[0] = blo(v.x); f[1] = bhi(v.x); f[2] = blo(v.y); f[3] = bhi(v.y);
  f[4] = blo(v.z); f[5] = bhi(v.z); f[6] = blo(v.w); f[7] = bhi(v.w);
}
// tanh-form gelu: 0.5v(1+tanh(.79788(v+.044715v^3))) = v - v/(e^{2z}+1); |err vs erf| ~3e-4
__device__ __forceinline__ float gelu_f(float v) {
  float u = v * v;
  float arg = v * fmaf(u, 0.0713548162f, 1.5957691216f);  // 2z
  float r = __builtin_amdgcn_rcpf(__expf(arg) + 1.0f);
  return fmaf(-v, r, v);
}
__device__ __forceinline__ f32x4 mfma_bf16(int4 a, int4 b, f32x4 c) {
  return __builtin_amdgcn_mfma_f32_16x16x32_bf16(
      __builtin_bit_cast(bf16x8, a), __builtin_bit_cast(bf16x8, b), c, 0, 0, 0);
}

// ---------------- weight prep: fp32 row-major -> bf16 B-fragment layout ----
__global__ __launch_bounds__(256) void prep_weights(
    const float* __restrict__ qkv_w, const float* __restrict__ proj_w,
    const float* __restrict__ ffn_w1, const float* __restrict__ ffn_w2,
    __bf16* __restrict__ ws) {
  int idx = blockIdx.x * 256 + threadIdx.x;
  if (idx >= WS_ELEMS) return;
  const float* src;
  int N, Ksz, lstride, base;
  if (idx < PROJF_OFF) { src = qkv_w; N = 192; Ksz = 64; lstride = 12288; base = idx; }
  else if (idx < F1F_OFF) { src = proj_w; N = 64; Ksz = 64; lstride = 4096; base = idx - PROJF_OFF; }
  else if (idx < F2F_OFF) { src = ffn_w1; N = 256; Ksz = 64; lstride = 16384; base = idx - F1F_OFF; }
  else { src = ffn_w2; N = 64; Ksz = 256; lstride = 16384; base = idx - F2F_OFF; }
  int layer = base / lstride, rem = base % lstride;
  int ntk = N / 16;
  int kt = rem / (ntk * 512); rem %= (ntk * 512);
  int nt = rem / 512;
  int lane = (rem % 512) / 8, j = rem % 8;
  int k = kt * 32 + (lane >> 4) * 8 + j;
  int n = nt * 16 + (lane & 15);
  ws[idx] = (__bf16)src[(size_t)layer * Ksz * N + (size_t)k * N + n];
}

__global__ __launch_bounds__(256, 5) void wtf_mfma(
    const float* __restrict__ x, const float* __restrict__ embed_w,
    const float* __restrict__ embed_b, const float* __restrict__ ln1_g,
    const float* __restrict__ ln1_b, const float* __restrict__ ln2_g,
    const float* __restrict__ ln2_b, const float* __restrict__ ffn_b1,
    const float* __restrict__ ffn_b2, const float* __restrict__ lnf_g,
    const float* __restrict__ lnf_b, const float* __restrict__ head_w,
    const float* __restrict__ head_b, const __bf16* __restrict__ wf,
    float* __restrict__ out) {
  const int tid = threadIdx.x;
  const int lane = tid & 63;
  const int w = tid >> 6;
  const int li16 = lane & 15;
  const int lg = lane >> 4;
  const int col = w * 16 + li16;

  __shared__ __align__(16) char lds_arena[ARENA_BYTES];
  __bf16(*actA)[APAD] = (__bf16(*)[APAD])(lds_arena + ACT_OFF);
  __bf16(*bufQ)[APAD] = (__bf16(*)[APAD])(lds_arena + BUFQ_OFF);
  __bf16(*bufK)[APAD] = (__bf16(*)[APAD])(lds_arena + BUFK_OFF);
  __bf16* bufT        = (__bf16*)(lds_arena + ACT_OFF);       // V^T [64][62]
  float(*hscr)[66]    = (float(*)[66])(lds_arena + BUFQ_OFF); // f32[64][66] spans Q+K
  __bf16* sP          = (__bf16*)(lds_arena + SPR_OFF);       // [bh*10+qt]*12 + kt
  float* sXf          = (float*)(lds_arena + SPR_OFF);        // 240 f32 (embed)
  float2(*sPart)[3]   = (float2(*)[3])(lds_arena + SPR_OFF);  // 60x3 (LN)
  float* sGB          = (float*)(lds_arena + SPR_OFF + 2048); // 128 f32 (LN)

  f32x4 h[MT];  // residual: h[mt][r] = h(row=mt*16+lg*4+r, col); rows>=60 garbage

  auto ln_reg = [&](const float* g, const float* b) {
#pragma unroll
    for (int mt = 0; mt < MT; ++mt)
#pragma unroll
      for (int r = 0; r < 4; ++r) hscr[mt * 16 + lg * 4 + r][col] = h[mt][r];
    if (tid < 64) { sGB[tid] = g[tid]; sGB[64 + tid] = b[tid]; }
    __syncthreads();
    const int c3 = (tid >= 120) ? 2 : (tid >= 60 ? 1 : 0);
    const int row = tid - c3 * 60;
    const int beg = (c3 == 0) ? 0 : (c3 == 1) ? 22 : 44;
    const int len2 = (c3 < 2) ? 11 : 10;
    if (tid < 180) {
      float s = 0.f, s2 = 0.f;
      for (int k = 0; k < len2; ++k) {
        float2 v = *(const float2*)&hscr[row][beg + 2 * k];
        s += v.x + v.y;
        s2 = fmaf(v.x, v.x, fmaf(v.y, v.y, s2));
      }
      sPart[row][c3] = make_float2(s, s2);
    }
    __syncthreads();
    if (tid < 180) {
      float2 p0 = sPart[row][0], p1 = sPart[row][1], p2 = sPart[row][2];
      float s = p0.x + p1.x + p2.x, s2 = p0.y + p1.y + p2.y;
      float m = s * 0.015625f;
      float rstd = rsqrtf(s2 * 0.015625f - m * m + EPS);
      for (int k = 0; k < len2; ++k) {
        int c = beg + 2 * k;
        float2 v = *(const float2*)&hscr[row][c];
        float v0 = (v.x - m) * rstd * sGB[c] + sGB[64 + c];
        float v1 = (v.y - m) * rstd * sGB[c + 1] + sGB[64 + c + 1];
        *(uint*)&actA[row][c] = pk2(v0, v1);
      }
    }
    __syncthreads();
  };

  // -------- stage x (240 f32) + embed into registers --------
  {
    int gx = blockIdx.x * (NB * 40) + tid;
    if (tid < NB * 40 && gx < 16384 * 40) sXf[tid] = x[gx];
  }
  __syncthreads();
  {
    float ew0 = embed_w[col], ew1 = embed_w[64 + col];
    float ew2 = embed_w[128 + col], ew3 = embed_w[192 + col];
    float eb = embed_b[col];
#pragma unroll
    for (int mt = 0; mt < MT; ++mt)
#pragma unroll
      for (int r = 0; r < 4; ++r) {
        int row = mt * 16 + lg * 4 + r;
        int t = (row * 43691) >> 18;          // row/6 (row<64)
        int b = row - t * 6;
        const float* xv = &sXf[b * 40 + t * 4];
        float acc = eb;
        acc = fmaf(xv[0], ew0, acc);
        acc = fmaf(xv[1], ew1, acc);
        acc = fmaf(xv[2], ew2, acc);
        acc = fmaf(xv[3], ew3, acc);
        h[mt][r] = acc;
      }
  }
  __syncthreads();

  for (int li = 0; li < 3; ++li) {
    const __bf16* qf = wf + li * 12288;
    const __bf16* pf = wf + PROJF_OFF + li * 4096;
    const __bf16* f1 = wf + F1F_OFF + li * 16384;
    const __bf16* f2 = wf + F2F_OFF + li * 16384;

    ln_reg(&ln1_g[li * 64], &ln1_b[li * 64]);

    // -------- fused QKV GEMM: Q->bufQ, K->bufK, V->regs --------
    uint2 vpk[MT];
    {
      int4 bq[3][2];
#pragma unroll
      for (int ii = 0; ii < 3; ++ii)
#pragma unroll
        for (int kt = 0; kt < 2; ++kt)
          bq[ii][kt] = ((const int4*)qf)[(kt * 12 + (w + 4 * ii)) * 64 + lane];
#pragma unroll
      for (int mt = 0; mt < MT; ++mt) {
        int arow = mt * 16 + li16;
        int4 a0 = *(const int4*)&actA[arow][lg * 8];
        int4 a1 = *(const int4*)&actA[arow][32 + lg * 8];
        f32x4 aq = {0.f, 0.f, 0.f, 0.f};
        aq = mfma_bf16(a0, bq[0][0], aq);
        aq = mfma_bf16(a1, bq[0][1], aq);
        f32x4 ak = {0.f, 0.f, 0.f, 0.f};
        ak = mfma_bf16(a0, bq[1][0], ak);
        ak = mfma_bf16(a1, bq[1][1], ak);
        f32x4 av = {0.f, 0.f, 0.f, 0.f};
        av = mfma_bf16(a0, bq[2][0], av);
        av = mfma_bf16(a1, bq[2][1], av);
        if (mt < MT - 1 || lg < 3) {  // rows < 60
#pragma unroll
          for (int r = 0; r < 4; ++r) bufQ[mt * 16 + lg * 4 + r][col] = (__bf16)aq[r];
#pragma unroll
          for (int r = 0; r < 4; ++r) bufK[mt * 16 + lg * 4 + r][col] = (__bf16)ak[r];
        }
        vpk[mt].x = pk2(av[0], av[1]);
        vpk[mt].y = pk2(av[2], av[3]);
      }
    }
    __syncthreads();

    // -------- scores+softmax: one (b,h,qt) row per thread, causal kt<=qt ----
    // || V^T write into bufT (actA region, dead)
    {
      if (tid < 240) {
        int qt = (tid * 43691) >> 20;  // tid/24
        int bh = tid - qt * 24;
        int b = bh >> 2, hh = bh & 3;
        int qrow = qt * 6 + b;
        float qv[16];
        {
          int4 qa = *(const int4*)&bufQ[qrow][hh * 16];
          int4 qb = *(const int4*)&bufQ[qrow][hh * 16 + 8];
          unpack8(qa, qv); unpack8(qb, qv + 8);
        }
        float sc[10];
#pragma unroll
        for (int kt = 0; kt < 10; ++kt) sc[kt] = 0.f;
        float mx = -1e30f;
        for (int kt = 0; kt <= qt; ++kt) {
          int4 ka = *(const int4*)&bufK[kt * 6 + b][hh * 16];
          int4 kb = *(const int4*)&bufK[kt * 6 + b][hh * 16 + 8];
          float kv[16]; unpack8(ka, kv); unpack8(kb, kv + 8);
          float d = 0.f;
#pragma unroll
          for (int i = 0; i < 16; ++i) d = fmaf(qv[i], kv[i], d);
          d *= 0.25f;
          sc[kt] = d;
          mx = fmaxf(mx, d);
        }
        float ssum = 0.f;
        for (int kt = 0; kt <= qt; ++kt) { sc[kt] = __expf(sc[kt] - mx); ssum += sc[kt]; }
        float inv = __builtin_amdgcn_rcpf(ssum);
        for (int kt = 0; kt <= qt; ++kt) sc[kt] *= inv;
        __bf16* prow = &sP[(bh * 10 + qt) * PPITCH];
#pragma unroll
        for (int i = 0; i < 5; ++i)
          *(uint*)&prow[2 * i] = pk2(sc[2 * i], sc[2 * i + 1]);
      }
      // V^T: bufT[col][row], rows<60
      const int coff = col * TPITCH;
#pragma unroll
      for (int mt = 0; mt < MT; ++mt) {
        if (mt < MT - 1 || lg < 3) {
          uint* dst = (uint*)&bufT[coff + mt * 16 + lg * 4];
          dst[0] = vpk[mt].x;
          dst[1] = vpk[mt].y;
        }
      }
    }
    __syncthreads();

    // -------- AV: y = P @ V -> bufK (K dead); V-cols + P-rows vectorized ----
    {
      const int hh = lane >> 4;
      const int b1 = (w + 4) % 6;
      const int b2 = w + 2;  // w<4 -> <6
      float vcol[3][10];
#pragma unroll
      for (int kt = 0; kt < 10; ++kt) {
        vcol[0][kt] = (float)bufT[lane * TPITCH + kt * 6 + w];
        vcol[1][kt] = (float)bufT[lane * TPITCH + kt * 6 + b1];
        vcol[2][kt] = (float)bufT[lane * TPITCH + kt * 6 + b2];
      }
      int rb = w, rq = 0;
#pragma unroll
      for (int it = 0; it < 15; ++it) {
        const int sel = it % 3;
        const __bf16* prow = &sP[((rb * 4 + hh) * 10 + rq) * PPITCH];
        uint2 pa = *(const uint2*)&prow[0];
        uint2 pb = *(const uint2*)&prow[4];
        uint pc = *(const uint*)&prow[8];
        float acc = 0.f;
        acc = fmaf(blo(pa.x), vcol[sel][0], acc);
        acc = fmaf(bhi(pa.x), vcol[sel][1], acc);
        acc = fmaf(blo(pa.y), vcol[sel][2], acc);
        acc = fmaf(bhi(pa.y), vcol[sel][3], acc);
        acc = fmaf(blo(pb.x), vcol[sel][4], acc);
        acc = fmaf(bhi(pb.x), vcol[sel][5], acc);
        acc = fmaf(blo(pb.y), vcol[sel][6], acc);
        acc = fmaf(bhi(pb.y), vcol[sel][7], acc);
        acc = fmaf(blo(pc), vcol[sel][8], acc);
        acc = fmaf(bhi(pc), vcol[sel][9], acc);
        bufK[w + 4 * it][lane] = (__bf16)acc;
        rb += 4;
        if (rb >= 6) { rb -= 6; ++rq; }
      }
    }
    __syncthreads();

    // -------- proj (reads y in bufK) + residual --------
    {
      int4 b0 = ((const int4*)pf)[(0 * 4 + w) * 64 + lane];
      int4 b1 = ((const int4*)pf)[(1 * 4 + w) * 64 + lane];
#pragma unroll
      for (int mt = 0; mt < MT; ++mt) {
        int arow = mt * 16 + li16;
        int4 a0 = *(const int4*)&bufK[arow][lg * 8];
        int4 a1 = *(const int4*)&bufK[arow][32 + lg * 8];
        f32x4 acc = {0.f, 0.f, 0.f, 0.f};
        acc = mfma_bf16(a0, b0, acc);
        acc = mfma_bf16(a1, b1, acc);
#pragma unroll
        for (int r = 0; r < 4; ++r) h[mt][r] += acc[r];
      }
    }
    __syncthreads();

    ln_reg(&ln2_g[li * 64], &ln2_b[li * 64]);

    // -------- fused FFN: 2 chunk-pairs --------
    {
#pragma unroll
      for (int cp = 0; cp < 2; ++cp) {
#pragma unroll
        for (int cc = 0; cc < 2; ++cc) {
          int c = cp * 2 + cc;
          int nt1 = c * 4 + w;
          int4 b0 = ((const int4*)f1)[(0 * 16 + nt1) * 64 + lane];
          int4 b1 = ((const int4*)f1)[(1 * 16 + nt1) * 64 + lane];
          float bias1 = ffn_b1[li * 256 + c * 64 + col];
          __bf16(*gbuf)[APAD] = cc ? bufK : bufQ;
#pragma unroll
          for (int mt = 0; mt < MT; ++mt) {
            int arow = mt * 16 + li16;
            int4 a0 = *(const int4*)&actA[arow][lg * 8];
            int4 a1 = *(const int4*)&actA[arow][32 + lg * 8];
            f32x4 acc = {0.f, 0.f, 0.f, 0.f};
            acc = mfma_bf16(a0, b0, acc);
            acc = mfma_bf16(a1, b1, acc);
            if (mt < MT - 1 || lg < 3) {
#pragma unroll
              for (int r = 0; r < 4; ++r)
                gbuf[mt * 16 + lg * 4 + r][col] = (__bf16)gelu_f(acc[r] + bias1);
            }
          }
        }
        __syncthreads();
        f32x4 acc2[MT];
#pragma unroll
        for (int mt = 0; mt < MT; ++mt) acc2[mt] = {0.f, 0.f, 0.f, 0.f};
#pragma unroll
        for (int cc = 0; cc < 2; ++cc) {
          int c = cp * 2 + cc;
          int4 c0 = ((const int4*)f2)[((c * 2 + 0) * 4 + w) * 64 + lane];
          int4 c1 = ((const int4*)f2)[((c * 2 + 1) * 4 + w) * 64 + lane];
          __bf16(*gbuf)[APAD] = cc ? bufK : bufQ;
#pragma unroll
          for (int mt = 0; mt < MT; ++mt) {
            int arow = mt * 16 + li16;
            int4 a0 = *(const int4*)&gbuf[arow][lg * 8];
            int4 a1 = *(const int4*)&gbuf[arow][32 + lg * 8];
            acc2[mt] = mfma_bf16(a0, c0, acc2[mt]);
            acc2[mt] = mfma_bf16(a1, c1, acc2[mt]);
          }
        }
#pragma unroll
        for (int mt = 0; mt < MT; ++mt)
#pragma unroll
          for (int r = 0; r < 4; ++r) h[mt][r] += acc2[mt][r];
        __syncthreads();
      }
      float bias2 = ffn_b2[li * 64 + col];
#pragma unroll
      for (int mt = 0; mt < MT; ++mt)
#pragma unroll
        for (int r = 0; r < 4; ++r) h[mt][r] += bias2;
    }
  }

  // -------- final LN (rows 54..59 = t9) + head --------
  {
#pragma unroll
    for (int r = 0; r < 4; ++r) {
      int row = 48 + lg * 4 + r;
      if (row >= 54 && row < 60) hscr[row - 54][col] = h[3][r];
    }
  }
  __syncthreads();
  float2* sFin = (float2*)(lds_arena + SPR_OFF);
  if (tid < NB) {
    float s = 0.f, s2 = 0.f;
#pragma unroll
    for (int i = 0; i < 64; ++i) { float v = hscr[tid][i]; s += v; s2 = fmaf(v, v, s2); }
    float m = s * 0.015625f;
    sFin[tid] = make_float2(m, rsqrtf(s2 * 0.015625f - m * m + EPS));
  }
  __syncthreads();
  if (tid < NB * 10) {
    int b = (tid * 6554) >> 16;  // tid/10
    int j = tid - b * 10;
    int gb = blockIdx.x * NB + b;
    if (gb < 16384) {
      float m = sFin[b].x, rstd = sFin[b].y;
      float acc = head_b[j];
#pragma unroll
      for (int d = 0; d < 64; ++d) {
        float z = (hscr[b][d] - m) * rstd * lnf_g[d] + lnf_b[d];
        acc = fmaf(z, head_w[d * 10 + j], acc);
      }
      out[(size_t)gb * 10 + j] = acc;
    }
  }
}

}  // namespace

extern "C" void kernel_launch(void* const* d_in, const int* in_sizes, int n_in,
                              void* d_out, int out_size, void* d_ws, size_t ws_size,
                              hipStream_t stream) {
  const float* x       = (const float*)d_in[0];
  const float* embed_w = (const float*)d_in[1];
  const float* embed_b = (const float*)d_in[2];
  const float* ln1_g   = (const float*)d_in[3];
  const float* ln1_b   = (const float*)d_in[4];
  const float* qkv_w   = (const float*)d_in[5];
  const float* proj_w  = (const float*)d_in[6];
  const float* ln2_g   = (const float*)d_in[7];
  const float* ln2_b   = (const float*)d_in[8];
  const float* ffn_w1  = (const float*)d_in[9];
  const float* ffn_b1  = (const float*)d_in[10];
  const float* ffn_w2  = (const float*)d_in[11];
  const float* ffn_b2  = (const float*)d_in[12];
  const float* lnf_g   = (const float*)d_in[13];
  const float* lnf_b   = (const float*)d_in[14];
  const float* head_w  = (const float*)d_in[15];
  const float* head_b  = (const float*)d_in[16];
  __bf16* wf = (__bf16*)d_ws;
  float* out = (float*)d_out;

  prep_weights<<<dim3((WS_ELEMS + 255) / 256), dim3(256), 0, stream>>>(
      qkv_w, proj_w, ffn_w1, ffn_w2, wf);
  wtf_mfma<<<dim3(NBLK), dim3(256), 0, stream>>>(
      x, embed_w, embed_b, ln1_g, ln1_b, ln2_g, ln2_b, ffn_b1, ffn_b2,
      lnf_g, lnf_b, head_w, head_b, wf, out);
}

// Round 8
// 321.419 us; speedup vs baseline: 1.0248x; 1.0248x over previous
//
#include <hip/hip_runtime.h>

namespace {

typedef __bf16 bf16x8 __attribute__((ext_vector_type(8)));
typedef float f32x4 __attribute__((ext_vector_type(4)));

constexpr int NB = 6;          // batches per block
constexpr int ROWS = 60;       // NB * T   (row = t*6 + b)
constexpr int MT = 4;          // M-tiles of 16 (rows 60..63 are masked garbage)
constexpr int APAD = 72;       // bf16 staging row pitch (144 B, 16B-aligned)
constexpr int TPITCH = 62;     // V^T pitch (124 B = 31 words, odd -> conflict-free)
constexpr int PPITCH = 12;     // P row pitch (24 B, 8B-aligned rows)
constexpr int NBLK = (16384 + NB - 1) / NB;  // 2731 (tail block partial)
constexpr float EPS = 1e-5f;

// ws bf16-fragment offsets (elements)
constexpr int PROJF_OFF = 36864;
constexpr int F1F_OFF = 49152;
constexpr int F2F_OFF = 98304;
constexpr int WS_ELEMS = 147456;

// LDS arena offsets (bytes)
constexpr int ACT_OFF = 0;           // bf16[60][72] 8640  (aliased: bufT bf16[64][62]=7936)
constexpr int BUFQ_OFF = 8640;       // bf16[60][72] 8640  (hscr f32[64][66]=16896 spans Q+K)
constexpr int BUFK_OFF = 17280;      // bf16[60][72] 8640  (also y destination)
constexpr int SPR_OFF = 25920;       // 5760: sP bf16[24*10*12] | sXf f32[240] | sPart+sGB
constexpr int ARENA_BYTES = 31680;   // 163840/31680 -> 5 blocks/CU

__device__ __forceinline__ uint pk2(float lo, float hi) {
  ushort ul = __builtin_bit_cast(ushort, (__bf16)lo);
  ushort uh = __builtin_bit_cast(ushort, (__bf16)hi);
  return (uint)ul | ((uint)uh << 16);
}
__device__ __forceinline__ float blo(uint u) { return __uint_as_float(u << 16); }
__device__ __forceinline__ float bhi(uint u) { return __uint_as_float(u & 0xffff0000u); }
__device__ __forceinline__ void unpack8(int4 v, float* f) {
  f[0] = blo(v.x); f[1] = bhi(v.x); f[2] = blo(v.y); f[3] = bhi(v.y);
  f[4] = blo(v.z); f[5] = bhi(v.z); f[6] = blo(v.w); f[7] = bhi(v.w);
}
// tanh-form gelu: 0.5v(1+tanh(.79788(v+.044715v^3))) = v - v/(e^{2z}+1); |err vs erf| ~3e-4
__device__ __forceinline__ float gelu_f(float v) {
  float u = v * v;
  float arg = v * fmaf(u, 0.0713548162f, 1.5957691216f);  // 2z
  float r = __builtin_amdgcn_rcpf(__expf(arg) + 1.0f);
  return fmaf(-v, r, v);
}
__device__ __forceinline__ f32x4 mfma_bf16(int4 a, int4 b, f32x4 c) {
  return __builtin_amdgcn_mfma_f32_16x16x32_bf16(
      __builtin_bit_cast(bf16x8, a), __builtin_bit_cast(bf16x8, b), c, 0, 0, 0);
}

// ---------------- weight prep: fp32 row-major -> bf16 B-fragment layout ----
__global__ __launch_bounds__(256) void prep_weights(
    const float* __restrict__ qkv_w, const float* __restrict__ proj_w,
    const float* __restrict__ ffn_w1, const float* __restrict__ ffn_w2,
    __bf16* __restrict__ ws) {
  int idx = blockIdx.x * 256 + threadIdx.x;
  if (idx >= WS_ELEMS) return;
  const float* src;
  int N, Ksz, lstride, base;
  if (idx < PROJF_OFF) { src = qkv_w; N = 192; Ksz = 64; lstride = 12288; base = idx; }
  else if (idx < F1F_OFF) { src = proj_w; N = 64; Ksz = 64; lstride = 4096; base = idx - PROJF_OFF; }
  else if (idx < F2F_OFF) { src = ffn_w1; N = 256; Ksz = 64; lstride = 16384; base = idx - F1F_OFF; }
  else { src = ffn_w2; N = 64; Ksz = 256; lstride = 16384; base = idx - F2F_OFF; }
  int layer = base / lstride, rem = base % lstride;
  int ntk = N / 16;
  int kt = rem / (ntk * 512); rem %= (ntk * 512);
  int nt = rem / 512;
  int lane = (rem % 512) / 8, j = rem % 8;
  int k = kt * 32 + (lane >> 4) * 8 + j;
  int n = nt * 16 + (lane & 15);
  ws[idx] = (__bf16)src[(size_t)layer * Ksz * N + (size_t)k * N + n];
}

__global__ __launch_bounds__(256, 5) void wtf_mfma(
    const float* __restrict__ x, const float* __restrict__ embed_w,
    const float* __restrict__ embed_b, const float* __restrict__ ln1_g,
    const float* __restrict__ ln1_b, const float* __restrict__ ln2_g,
    const float* __restrict__ ln2_b, const float* __restrict__ ffn_b1,
    const float* __restrict__ ffn_b2, const float* __restrict__ lnf_g,
    const float* __restrict__ lnf_b, const float* __restrict__ head_w,
    const float* __restrict__ head_b, const __bf16* __restrict__ wf,
    float* __restrict__ out) {
  const int tid = threadIdx.x;
  const int lane = tid & 63;
  const int w = tid >> 6;
  const int li16 = lane & 15;
  const int lg = lane >> 4;
  const int col = w * 16 + li16;

  __shared__ __align__(16) char lds_arena[ARENA_BYTES];
  __bf16(*actA)[APAD] = (__bf16(*)[APAD])(lds_arena + ACT_OFF);
  __bf16(*bufQ)[APAD] = (__bf16(*)[APAD])(lds_arena + BUFQ_OFF);
  __bf16(*bufK)[APAD] = (__bf16(*)[APAD])(lds_arena + BUFK_OFF);
  __bf16* bufT        = (__bf16*)(lds_arena + ACT_OFF);       // V^T [64][62]
  float(*hscr)[66]    = (float(*)[66])(lds_arena + BUFQ_OFF); // f32[64][66] spans Q+K
  __bf16* sP          = (__bf16*)(lds_arena + SPR_OFF);       // [bh*10+qt]*12 + kt
  float* sXf          = (float*)(lds_arena + SPR_OFF);        // 240 f32 (embed)
  float2(*sPart)[3]   = (float2(*)[3])(lds_arena + SPR_OFF);  // 60x3 (LN)
  float* sGB          = (float*)(lds_arena + SPR_OFF + 2048); // 128 f32 (LN)

  f32x4 h[MT];  // residual: h[mt][r] = h(row=mt*16+lg*4+r, col); rows>=60 garbage

  auto ln_reg = [&](const float* g, const float* b) {
#pragma unroll
    for (int mt = 0; mt < MT; ++mt)
#pragma unroll
      for (int r = 0; r < 4; ++r) hscr[mt * 16 + lg * 4 + r][col] = h[mt][r];
    if (tid < 64) { sGB[tid] = g[tid]; sGB[64 + tid] = b[tid]; }
    __syncthreads();
    const int c3 = (tid >= 120) ? 2 : (tid >= 60 ? 1 : 0);
    const int row = tid - c3 * 60;
    const int beg = (c3 == 0) ? 0 : (c3 == 1) ? 22 : 44;
    const int len2 = (c3 < 2) ? 11 : 10;
    if (tid < 180) {
      float s = 0.f, s2 = 0.f;
      for (int k = 0; k < len2; ++k) {
        float2 v = *(const float2*)&hscr[row][beg + 2 * k];
        s += v.x + v.y;
        s2 = fmaf(v.x, v.x, fmaf(v.y, v.y, s2));
      }
      sPart[row][c3] = make_float2(s, s2);
    }
    __syncthreads();
    if (tid < 180) {
      float2 p0 = sPart[row][0], p1 = sPart[row][1], p2 = sPart[row][2];
      float s = p0.x + p1.x + p2.x, s2 = p0.y + p1.y + p2.y;
      float m = s * 0.015625f;
      float rstd = rsqrtf(s2 * 0.015625f - m * m + EPS);
      for (int k = 0; k < len2; ++k) {
        int c = beg + 2 * k;
        float2 v = *(const float2*)&hscr[row][c];
        float v0 = (v.x - m) * rstd * sGB[c] + sGB[64 + c];
        float v1 = (v.y - m) * rstd * sGB[c + 1] + sGB[64 + c + 1];
        *(uint*)&actA[row][c] = pk2(v0, v1);
      }
    }
    __syncthreads();
  };

  // -------- stage x (240 f32) + embed into registers --------
  {
    int gx = blockIdx.x * (NB * 40) + tid;
    if (tid < NB * 40 && gx < 16384 * 40) sXf[tid] = x[gx];
  }
  __syncthreads();
  {
    float ew0 = embed_w[col], ew1 = embed_w[64 + col];
    float ew2 = embed_w[128 + col], ew3 = embed_w[192 + col];
    float eb = embed_b[col];
#pragma unroll
    for (int mt = 0; mt < MT; ++mt)
#pragma unroll
      for (int r = 0; r < 4; ++r) {
        int row = mt * 16 + lg * 4 + r;
        int t = (row * 43691) >> 18;          // row/6 (row<64)
        int b = row - t * 6;
        const float* xv = &sXf[b * 40 + t * 4];
        float acc = eb;
        acc = fmaf(xv[0], ew0, acc);
        acc = fmaf(xv[1], ew1, acc);
        acc = fmaf(xv[2], ew2, acc);
        acc = fmaf(xv[3], ew3, acc);
        h[mt][r] = acc;
      }
  }
  __syncthreads();

  for (int li = 0; li < 3; ++li) {
    const __bf16* qf = wf + li * 12288;
    const __bf16* pf = wf + PROJF_OFF + li * 4096;
    const __bf16* f1 = wf + F1F_OFF + li * 16384;
    const __bf16* f2 = wf + F2F_OFF + li * 16384;

    ln_reg(&ln1_g[li * 64], &ln1_b[li * 64]);

    // -------- fused QKV GEMM: Q->bufQ, K->bufK, V->regs --------
    uint2 vpk[MT];
    {
      int4 bq[3][2];
#pragma unroll
      for (int ii = 0; ii < 3; ++ii)
#pragma unroll
        for (int kt = 0; kt < 2; ++kt)
          bq[ii][kt] = ((const int4*)qf)[(kt * 12 + (w + 4 * ii)) * 64 + lane];
#pragma unroll
      for (int mt = 0; mt < MT; ++mt) {
        int arow = mt * 16 + li16;
        int4 a0 = *(const int4*)&actA[arow][lg * 8];
        int4 a1 = *(const int4*)&actA[arow][32 + lg * 8];
        f32x4 aq = {0.f, 0.f, 0.f, 0.f};
        aq = mfma_bf16(a0, bq[0][0], aq);
        aq = mfma_bf16(a1, bq[0][1], aq);
        f32x4 ak = {0.f, 0.f, 0.f, 0.f};
        ak = mfma_bf16(a0, bq[1][0], ak);
        ak = mfma_bf16(a1, bq[1][1], ak);
        f32x4 av = {0.f, 0.f, 0.f, 0.f};
        av = mfma_bf16(a0, bq[2][0], av);
        av = mfma_bf16(a1, bq[2][1], av);
        if (mt < MT - 1 || lg < 3) {  // rows < 60
#pragma unroll
          for (int r = 0; r < 4; ++r) bufQ[mt * 16 + lg * 4 + r][col] = (__bf16)aq[r];
#pragma unroll
          for (int r = 0; r < 4; ++r) bufK[mt * 16 + lg * 4 + r][col] = (__bf16)ak[r];
        }
        vpk[mt].x = pk2(av[0], av[1]);
        vpk[mt].y = pk2(av[2], av[3]);
      }
    }
    __syncthreads();

    // -------- scores+softmax: one (b,h,qt) row per thread; FIXED-BOUND loops
    // (v7 bug: dynamic `kt<=qt` bounds sent sc[] to scratch -> 163MB spill traffic)
    // || V^T write into bufT (actA region, dead)
    {
      if (tid < 240) {
        int qt = (tid * 43691) >> 20;  // tid/24
        int bh = tid - qt * 24;
        int b = bh >> 2, hh = bh & 3;
        int qrow = qt * 6 + b;
        float qv[16];
        {
          int4 qa = *(const int4*)&bufQ[qrow][hh * 16];
          int4 qb = *(const int4*)&bufQ[qrow][hh * 16 + 8];
          unpack8(qa, qv); unpack8(qb, qv + 8);
        }
        float sc[10], mx = -1e30f;
#pragma unroll
        for (int kt = 0; kt < 10; ++kt) {
          int4 ka = *(const int4*)&bufK[kt * 6 + b][hh * 16];
          int4 kb = *(const int4*)&bufK[kt * 6 + b][hh * 16 + 8];
          float kv[16]; unpack8(ka, kv); unpack8(kb, kv + 8);
          float d = 0.f;
#pragma unroll
          for (int i = 0; i < 16; ++i) d = fmaf(qv[i], kv[i], d);
          sc[kt] = (kt <= qt) ? d * 0.25f : -1e30f;
          mx = fmaxf(mx, sc[kt]);
        }
        float ssum = 0.f;
#pragma unroll
        for (int kt = 0; kt < 10; ++kt) { sc[kt] = __expf(sc[kt] - mx); ssum += sc[kt]; }
        float inv = __builtin_amdgcn_rcpf(ssum);
        __bf16* prow = &sP[(bh * 10 + qt) * PPITCH];
#pragma unroll
        for (int i = 0; i < 5; ++i)
          *(uint*)&prow[2 * i] = pk2(sc[2 * i] * inv, sc[2 * i + 1] * inv);
      }
      // V^T: bufT[col][row], rows<60
      const int coff = col * TPITCH;
#pragma unroll
      for (int mt = 0; mt < MT; ++mt) {
        if (mt < MT - 1 || lg < 3) {
          uint* dst = (uint*)&bufT[coff + mt * 16 + lg * 4];
          dst[0] = vpk[mt].x;
          dst[1] = vpk[mt].y;
        }
      }
    }
    __syncthreads();

    // -------- AV: y = P @ V -> bufK (K dead); V-cols + P-rows vectorized ----
    {
      const int hh = lane >> 4;
      const int b1 = (w + 4) % 6;
      const int b2 = w + 2;  // w<4 -> <6
      float vcol[3][10];
#pragma unroll
      for (int kt = 0; kt < 10; ++kt) {
        vcol[0][kt] = (float)bufT[lane * TPITCH + kt * 6 + w];
        vcol[1][kt] = (float)bufT[lane * TPITCH + kt * 6 + b1];
        vcol[2][kt] = (float)bufT[lane * TPITCH + kt * 6 + b2];
      }
      int rb = w, rq = 0;
#pragma unroll
      for (int it = 0; it < 15; ++it) {
        const int sel = it % 3;
        const __bf16* prow = &sP[((rb * 4 + hh) * 10 + rq) * PPITCH];
        uint2 pa = *(const uint2*)&prow[0];
        uint2 pb = *(const uint2*)&prow[4];
        uint pc = *(const uint*)&prow[8];
        float acc = 0.f;
        acc = fmaf(blo(pa.x), vcol[sel][0], acc);
        acc = fmaf(bhi(pa.x), vcol[sel][1], acc);
        acc = fmaf(blo(pa.y), vcol[sel][2], acc);
        acc = fmaf(bhi(pa.y), vcol[sel][3], acc);
        acc = fmaf(blo(pb.x), vcol[sel][4], acc);
        acc = fmaf(bhi(pb.x), vcol[sel][5], acc);
        acc = fmaf(blo(pb.y), vcol[sel][6], acc);
        acc = fmaf(bhi(pb.y), vcol[sel][7], acc);
        acc = fmaf(blo(pc), vcol[sel][8], acc);
        acc = fmaf(bhi(pc), vcol[sel][9], acc);
        bufK[w + 4 * it][lane] = (__bf16)acc;
        rb += 4;
        if (rb >= 6) { rb -= 6; ++rq; }
      }
    }
    __syncthreads();

    // -------- proj (reads y in bufK) + residual --------
    {
      int4 b0 = ((const int4*)pf)[(0 * 4 + w) * 64 + lane];
      int4 b1 = ((const int4*)pf)[(1 * 4 + w) * 64 + lane];
#pragma unroll
      for (int mt = 0; mt < MT; ++mt) {
        int arow = mt * 16 + li16;
        int4 a0 = *(const int4*)&bufK[arow][lg * 8];
        int4 a1 = *(const int4*)&bufK[arow][32 + lg * 8];
        f32x4 acc = {0.f, 0.f, 0.f, 0.f};
        acc = mfma_bf16(a0, b0, acc);
        acc = mfma_bf16(a1, b1, acc);
#pragma unroll
        for (int r = 0; r < 4; ++r) h[mt][r] += acc[r];
      }
    }
    __syncthreads();

    ln_reg(&ln2_g[li * 64], &ln2_b[li * 64]);

    // -------- fused FFN: 2 chunk-pairs --------
    {
#pragma unroll
      for (int cp = 0; cp < 2; ++cp) {
#pragma unroll
        for (int cc = 0; cc < 2; ++cc) {
          int c = cp * 2 + cc;
          int nt1 = c * 4 + w;
          int4 b0 = ((const int4*)f1)[(0 * 16 + nt1) * 64 + lane];
          int4 b1 = ((const int4*)f1)[(1 * 16 + nt1) * 64 + lane];
          float bias1 = ffn_b1[li * 256 + c * 64 + col];
          __bf16(*gbuf)[APAD] = cc ? bufK : bufQ;
#pragma unroll
          for (int mt = 0; mt < MT; ++mt) {
            int arow = mt * 16 + li16;
            int4 a0 = *(const int4*)&actA[arow][lg * 8];
            int4 a1 = *(const int4*)&actA[arow][32 + lg * 8];
            f32x4 acc = {0.f, 0.f, 0.f, 0.f};
            acc = mfma_bf16(a0, b0, acc);
            acc = mfma_bf16(a1, b1, acc);
            if (mt < MT - 1 || lg < 3) {
#pragma unroll
              for (int r = 0; r < 4; ++r)
                gbuf[mt * 16 + lg * 4 + r][col] = (__bf16)gelu_f(acc[r] + bias1);
            }
          }
        }
        __syncthreads();
        f32x4 acc2[MT];
#pragma unroll
        for (int mt = 0; mt < MT; ++mt) acc2[mt] = {0.f, 0.f, 0.f, 0.f};
#pragma unroll
        for (int cc = 0; cc < 2; ++cc) {
          int c = cp * 2 + cc;
          int4 c0 = ((const int4*)f2)[((c * 2 + 0) * 4 + w) * 64 + lane];
          int4 c1 = ((const int4*)f2)[((c * 2 + 1) * 4 + w) * 64 + lane];
          __bf16(*gbuf)[APAD] = cc ? bufK : bufQ;
#pragma unroll
          for (int mt = 0; mt < MT; ++mt) {
            int arow = mt * 16 + li16;
            int4 a0 = *(const int4*)&gbuf[arow][lg * 8];
            int4 a1 = *(const int4*)&gbuf[arow][32 + lg * 8];
            acc2[mt] = mfma_bf16(a0, c0, acc2[mt]);
            acc2[mt] = mfma_bf16(a1, c1, acc2[mt]);
          }
        }
#pragma unroll
        for (int mt = 0; mt < MT; ++mt)
#pragma unroll
          for (int r = 0; r < 4; ++r) h[mt][r] += acc2[mt][r];
        __syncthreads();
      }
      float bias2 = ffn_b2[li * 64 + col];
#pragma unroll
      for (int mt = 0; mt < MT; ++mt)
#pragma unroll
        for (int r = 0; r < 4; ++r) h[mt][r] += bias2;
    }
  }

  // -------- final LN (rows 54..59 = t9) + head --------
  {
#pragma unroll
    for (int r = 0; r < 4; ++r) {
      int row = 48 + lg * 4 + r;
      if (row >= 54 && row < 60) hscr[row - 54][col] = h[3][r];
    }
  }
  __syncthreads();
  float2* sFin = (float2*)(lds_arena + SPR_OFF);
  if (tid < NB) {
    float s = 0.f, s2 = 0.f;
#pragma unroll
    for (int i = 0; i < 64; ++i) { float v = hscr[tid][i]; s += v; s2 = fmaf(v, v, s2); }
    float m = s * 0.015625f;
    sFin[tid] = make_float2(m, rsqrtf(s2 * 0.015625f - m * m + EPS));
  }
  __syncthreads();
  if (tid < NB * 10) {
    int b = (tid * 6554) >> 16;  // tid/10
    int j = tid - b * 10;
    int gb = blockIdx.x * NB + b;
    if (gb < 16384) {
      float m = sFin[b].x, rstd = sFin[b].y;
      float acc = head_b[j];
#pragma unroll
      for (int d = 0; d < 64; ++d) {
        float z = (hscr[b][d] - m) * rstd * lnf_g[d] + lnf_b[d];
        acc = fmaf(z, head_w[d * 10 + j], acc);
      }
      out[(size_t)gb * 10 + j] = acc;
    }
  }
}

}  // namespace

extern "C" void kernel_launch(void* const* d_in, const int* in_sizes, int n_in,
                              void* d_out, int out_size, void* d_ws, size_t ws_size,
                              hipStream_t stream) {
  const float* x       = (const float*)d_in[0];
  const float* embed_w = (const float*)d_in[1];
  const float* embed_b = (const float*)d_in[2];
  const float* ln1_g   = (const float*)d_in[3];
  const float* ln1_b   = (const float*)d_in[4];
  const float* qkv_w   = (const float*)d_in[5];
  const float* proj_w  = (const float*)d_in[6];
  const float* ln2_g   = (const float*)d_in[7];
  const float* ln2_b   = (const float*)d_in[8];
  const float* ffn_w1  = (const float*)d_in[9];
  const float* ffn_b1  = (const float*)d_in[10];
  const float* ffn_w2  = (const float*)d_in[11];
  const float* ffn_b2  = (const float*)d_in[12];
  const float* lnf_g   = (const float*)d_in[13];
  const float* lnf_b   = (const float*)d_in[14];
  const float* head_w  = (const float*)d_in[15];
  const float* head_b  = (const float*)d_in[16];
  __bf16* wf = (__bf16*)d_ws;
  float* out = (float*)d_out;

  prep_weights<<<dim3((WS_ELEMS + 255) / 256), dim3(256), 0, stream>>>(
      qkv_w, proj_w, ffn_w1, ffn_w2, wf);
  wtf_mfma<<<dim3(NBLK), dim3(256), 0, stream>>>(
      x, embed_w, embed_b, ln1_g, ln1_b, ln2_g, ln2_b, ffn_b1, ffn_b2,
      lnf_g, lnf_b, head_w, head_b, wf, out);
}

// Round 9
// 255.510 us; speedup vs baseline: 1.2892x; 1.2579x over previous
//
#include <hip/hip_runtime.h>

namespace {

typedef __bf16 bf16x8 __attribute__((ext_vector_type(8)));
typedef float f32x4 __attribute__((ext_vector_type(4)));

constexpr int NB = 6;          // batches per block
constexpr int ROWS = 60;       // NB * T   (row = t*6 + b)
constexpr int MT = 4;          // M-tiles of 16 (rows 60..63 are masked garbage)
constexpr int APAD = 72;       // bf16 staging row pitch (144 B, 16B-aligned)
constexpr int TPITCH = 62;     // V^T pitch (124 B = 31 words, odd -> conflict-free)
constexpr int PPITCH = 12;     // P row pitch (24 B, 8B-aligned rows)
constexpr int NBLK = (16384 + NB - 1) / NB;  // 2731 (tail block partial)
constexpr float EPS = 1e-5f;

// ws bf16-fragment offsets (elements)
constexpr int PROJF_OFF = 36864;
constexpr int F1F_OFF = 49152;
constexpr int F2F_OFF = 98304;
constexpr int WS_ELEMS = 147456;

// LDS arena offsets (bytes)
constexpr int ACT_OFF = 0;           // bf16[60][72] 8640  (aliased: bufT bf16[64][62]=7936)
constexpr int BUFQ_OFF = 8640;       // bf16[60][72] 8640  (hscr f32[64][66]=16896 spans Q+K)
constexpr int BUFK_OFF = 17280;      // bf16[60][72] 8640  (also y destination)
constexpr int SPR_OFF = 25920;       // 5760: sP bf16[24*10*12] | sXf f32[240] | sPart+sGB
constexpr int ARENA_BYTES = 31680;   // LDS would allow 5 blocks/CU; VGPR caps at 4

__device__ __forceinline__ uint pk2(float lo, float hi) {
  ushort ul = __builtin_bit_cast(ushort, (__bf16)lo);
  ushort uh = __builtin_bit_cast(ushort, (__bf16)hi);
  return (uint)ul | ((uint)uh << 16);
}
__device__ __forceinline__ float blo(uint u) { return __uint_as_float(u << 16); }
__device__ __forceinline__ float bhi(uint u) { return __uint_as_float(u & 0xffff0000u); }
__device__ __forceinline__ void unpack8(int4 v, float* f) {
  f[0] = blo(v.x); f[1] = bhi(v.x); f[2] = blo(v.y); f[3] = bhi(v.y);
  f[4] = blo(v.z); f[5] = bhi(v.z); f[6] = blo(v.w); f[7] = bhi(v.w);
}
// tanh-form gelu: 0.5v(1+tanh(.79788(v+.044715v^3))) = v - v/(e^{2z}+1); |err vs erf| ~3e-4
__device__ __forceinline__ float gelu_f(float v) {
  float u = v * v;
  float arg = v * fmaf(u, 0.0713548162f, 1.5957691216f);  // 2z
  float r = __builtin_amdgcn_rcpf(__expf(arg) + 1.0f);
  return fmaf(-v, r, v);
}
__device__ __forceinline__ f32x4 mfma_bf16(int4 a, int4 b, f32x4 c) {
  return __builtin_amdgcn_mfma_f32_16x16x32_bf16(
      __builtin_bit_cast(bf16x8, a), __builtin_bit_cast(bf16x8, b), c, 0, 0, 0);
}

// ---------------- weight prep: fp32 row-major -> bf16 B-fragment layout ----
__global__ __launch_bounds__(256) void prep_weights(
    const float* __restrict__ qkv_w, const float* __restrict__ proj_w,
    const float* __restrict__ ffn_w1, const float* __restrict__ ffn_w2,
    __bf16* __restrict__ ws) {
  int idx = blockIdx.x * 256 + threadIdx.x;
  if (idx >= WS_ELEMS) return;
  const float* src;
  int N, Ksz, lstride, base;
  if (idx < PROJF_OFF) { src = qkv_w; N = 192; Ksz = 64; lstride = 12288; base = idx; }
  else if (idx < F1F_OFF) { src = proj_w; N = 64; Ksz = 64; lstride = 4096; base = idx - PROJF_OFF; }
  else if (idx < F2F_OFF) { src = ffn_w1; N = 256; Ksz = 64; lstride = 16384; base = idx - F1F_OFF; }
  else { src = ffn_w2; N = 64; Ksz = 256; lstride = 16384; base = idx - F2F_OFF; }
  int layer = base / lstride, rem = base % lstride;
  int ntk = N / 16;
  int kt = rem / (ntk * 512); rem %= (ntk * 512);
  int nt = rem / 512;
  int lane = (rem % 512) / 8, j = rem % 8;
  int k = kt * 32 + (lane >> 4) * 8 + j;
  int n = nt * 16 + (lane & 15);
  ws[idx] = (__bf16)src[(size_t)layer * Ksz * N + (size_t)k * N + n];
}

__global__ __launch_bounds__(256, 4) void wtf_mfma(
    const float* __restrict__ x, const float* __restrict__ embed_w,
    const float* __restrict__ embed_b, const float* __restrict__ ln1_g,
    const float* __restrict__ ln1_b, const float* __restrict__ ln2_g,
    const float* __restrict__ ln2_b, const float* __restrict__ ffn_b1,
    const float* __restrict__ ffn_b2, const float* __restrict__ lnf_g,
    const float* __restrict__ lnf_b, const float* __restrict__ head_w,
    const float* __restrict__ head_b, const __bf16* __restrict__ wf,
    float* __restrict__ out) {
  const int tid = threadIdx.x;
  const int lane = tid & 63;
  const int w = tid >> 6;
  const int li16 = lane & 15;
  const int lg = lane >> 4;
  const int col = w * 16 + li16;

  __shared__ __align__(16) char lds_arena[ARENA_BYTES];
  __bf16(*actA)[APAD] = (__bf16(*)[APAD])(lds_arena + ACT_OFF);
  __bf16(*bufQ)[APAD] = (__bf16(*)[APAD])(lds_arena + BUFQ_OFF);
  __bf16(*bufK)[APAD] = (__bf16(*)[APAD])(lds_arena + BUFK_OFF);
  __bf16* bufT        = (__bf16*)(lds_arena + ACT_OFF);       // V^T [64][62]
  float(*hscr)[66]    = (float(*)[66])(lds_arena + BUFQ_OFF); // f32[64][66] spans Q+K
  __bf16* sP          = (__bf16*)(lds_arena + SPR_OFF);       // [bh*10+qt]*12 + kt
  float* sXf          = (float*)(lds_arena + SPR_OFF);        // 240 f32 (embed)
  float2(*sPart)[3]   = (float2(*)[3])(lds_arena + SPR_OFF);  // 60x3 (LN)
  float* sGB          = (float*)(lds_arena + SPR_OFF + 2048); // 128 f32 (LN)

  f32x4 h[MT];  // residual: h[mt][r] = h(row=mt*16+lg*4+r, col); rows>=60 garbage

  auto ln_reg = [&](const float* g, const float* b) {
#pragma unroll
    for (int mt = 0; mt < MT; ++mt)
#pragma unroll
      for (int r = 0; r < 4; ++r) hscr[mt * 16 + lg * 4 + r][col] = h[mt][r];
    if (tid < 64) { sGB[tid] = g[tid]; sGB[64 + tid] = b[tid]; }
    __syncthreads();
    const int c3 = (tid >= 120) ? 2 : (tid >= 60 ? 1 : 0);
    const int row = tid - c3 * 60;
    const int beg = (c3 == 0) ? 0 : (c3 == 1) ? 22 : 44;
    const int len2 = (c3 < 2) ? 11 : 10;
    if (tid < 180) {
      float s = 0.f, s2 = 0.f;
      for (int k = 0; k < len2; ++k) {
        float2 v = *(const float2*)&hscr[row][beg + 2 * k];
        s += v.x + v.y;
        s2 = fmaf(v.x, v.x, fmaf(v.y, v.y, s2));
      }
      sPart[row][c3] = make_float2(s, s2);
    }
    __syncthreads();
    if (tid < 180) {
      float2 p0 = sPart[row][0], p1 = sPart[row][1], p2 = sPart[row][2];
      float s = p0.x + p1.x + p2.x, s2 = p0.y + p1.y + p2.y;
      float m = s * 0.015625f;
      float rstd = rsqrtf(s2 * 0.015625f - m * m + EPS);
      for (int k = 0; k < len2; ++k) {
        int c = beg + 2 * k;
        float2 v = *(const float2*)&hscr[row][c];
        float v0 = (v.x - m) * rstd * sGB[c] + sGB[64 + c];
        float v1 = (v.y - m) * rstd * sGB[c + 1] + sGB[64 + c + 1];
        *(uint*)&actA[row][c] = pk2(v0, v1);
      }
    }
    __syncthreads();
  };

  // -------- stage x (240 f32) + embed into registers --------
  {
    int gx = blockIdx.x * (NB * 40) + tid;
    if (tid < NB * 40 && gx < 16384 * 40) sXf[tid] = x[gx];
  }
  __syncthreads();
  {
    float ew0 = embed_w[col], ew1 = embed_w[64 + col];
    float ew2 = embed_w[128 + col], ew3 = embed_w[192 + col];
    float eb = embed_b[col];
#pragma unroll
    for (int mt = 0; mt < MT; ++mt)
#pragma unroll
      for (int r = 0; r < 4; ++r) {
        int row = mt * 16 + lg * 4 + r;
        int t = (row * 43691) >> 18;          // row/6 (row<64)
        int b = row - t * 6;
        const float* xv = &sXf[b * 40 + t * 4];
        float acc = eb;
        acc = fmaf(xv[0], ew0, acc);
        acc = fmaf(xv[1], ew1, acc);
        acc = fmaf(xv[2], ew2, acc);
        acc = fmaf(xv[3], ew3, acc);
        h[mt][r] = acc;
      }
  }
  __syncthreads();

  for (int li = 0; li < 3; ++li) {
    const __bf16* qf = wf + li * 12288;
    const __bf16* pf = wf + PROJF_OFF + li * 4096;
    const __bf16* f1 = wf + F1F_OFF + li * 16384;
    const __bf16* f2 = wf + F2F_OFF + li * 16384;

    ln_reg(&ln1_g[li * 64], &ln1_b[li * 64]);

    // -------- fused QKV GEMM: Q->bufQ, K->bufK, V->regs --------
    uint2 vpk[MT];
    {
      int4 bq[3][2];
#pragma unroll
      for (int ii = 0; ii < 3; ++ii)
#pragma unroll
        for (int kt = 0; kt < 2; ++kt)
          bq[ii][kt] = ((const int4*)qf)[(kt * 12 + (w + 4 * ii)) * 64 + lane];
#pragma unroll
      for (int mt = 0; mt < MT; ++mt) {
        int arow = mt * 16 + li16;
        int4 a0 = *(const int4*)&actA[arow][lg * 8];
        int4 a1 = *(const int4*)&actA[arow][32 + lg * 8];
        f32x4 aq = {0.f, 0.f, 0.f, 0.f};
        aq = mfma_bf16(a0, bq[0][0], aq);
        aq = mfma_bf16(a1, bq[0][1], aq);
        f32x4 ak = {0.f, 0.f, 0.f, 0.f};
        ak = mfma_bf16(a0, bq[1][0], ak);
        ak = mfma_bf16(a1, bq[1][1], ak);
        f32x4 av = {0.f, 0.f, 0.f, 0.f};
        av = mfma_bf16(a0, bq[2][0], av);
        av = mfma_bf16(a1, bq[2][1], av);
        if (mt < MT - 1 || lg < 3) {  // rows < 60
#pragma unroll
          for (int r = 0; r < 4; ++r) bufQ[mt * 16 + lg * 4 + r][col] = (__bf16)aq[r];
#pragma unroll
          for (int r = 0; r < 4; ++r) bufK[mt * 16 + lg * 4 + r][col] = (__bf16)ak[r];
        }
        vpk[mt].x = pk2(av[0], av[1]);
        vpk[mt].y = pk2(av[2], av[3]);
      }
    }
    __syncthreads();

    // -------- scores+softmax: one (b,h,qt) row per thread; fixed-bound loops
    // || V^T write into bufT (actA region, dead)
    {
      if (tid < 240) {
        int qt = (tid * 43691) >> 20;  // tid/24
        int bh = tid - qt * 24;
        int b = bh >> 2, hh = bh & 3;
        int qrow = qt * 6 + b;
        float qv[16];
        {
          int4 qa = *(const int4*)&bufQ[qrow][hh * 16];
          int4 qb = *(const int4*)&bufQ[qrow][hh * 16 + 8];
          unpack8(qa, qv); unpack8(qb, qv + 8);
        }
        float sc[10], mx = -1e30f;
#pragma unroll
        for (int kt = 0; kt < 10; ++kt) {
          int4 ka = *(const int4*)&bufK[kt * 6 + b][hh * 16];
          int4 kb = *(const int4*)&bufK[kt * 6 + b][hh * 16 + 8];
          float kv[16]; unpack8(ka, kv); unpack8(kb, kv + 8);
          float d = 0.f;
#pragma unroll
          for (int i = 0; i < 16; ++i) d = fmaf(qv[i], kv[i], d);
          sc[kt] = (kt <= qt) ? d * 0.25f : -1e30f;
          mx = fmaxf(mx, sc[kt]);
        }
        float ssum = 0.f;
#pragma unroll
        for (int kt = 0; kt < 10; ++kt) { sc[kt] = __expf(sc[kt] - mx); ssum += sc[kt]; }
        float inv = __builtin_amdgcn_rcpf(ssum);
        __bf16* prow = &sP[(bh * 10 + qt) * PPITCH];
#pragma unroll
        for (int i = 0; i < 5; ++i)
          *(uint*)&prow[2 * i] = pk2(sc[2 * i] * inv, sc[2 * i + 1] * inv);
      }
      // V^T: bufT[col][row], rows<60
      const int coff = col * TPITCH;
#pragma unroll
      for (int mt = 0; mt < MT; ++mt) {
        if (mt < MT - 1 || lg < 3) {
          uint* dst = (uint*)&bufT[coff + mt * 16 + lg * 4];
          dst[0] = vpk[mt].x;
          dst[1] = vpk[mt].y;
        }
      }
    }
    __syncthreads();

    // -------- AV: y = P @ V -> bufK (K dead); V-cols + P-rows vectorized ----
    {
      const int hh = lane >> 4;
      const int b1 = (w + 4) % 6;
      const int b2 = w + 2;  // w<4 -> <6
      float vcol[3][10];
#pragma unroll
      for (int kt = 0; kt < 10; ++kt) {
        vcol[0][kt] = (float)bufT[lane * TPITCH + kt * 6 + w];
        vcol[1][kt] = (float)bufT[lane * TPITCH + kt * 6 + b1];
        vcol[2][kt] = (float)bufT[lane * TPITCH + kt * 6 + b2];
      }
      int rb = w, rq = 0;
#pragma unroll
      for (int it = 0; it < 15; ++it) {
        const int sel = it % 3;
        const __bf16* prow = &sP[((rb * 4 + hh) * 10 + rq) * PPITCH];
        uint2 pa = *(const uint2*)&prow[0];
        uint2 pb = *(const uint2*)&prow[4];
        uint pc = *(const uint*)&prow[8];
        float acc = 0.f;
        acc = fmaf(blo(pa.x), vcol[sel][0], acc);
        acc = fmaf(bhi(pa.x), vcol[sel][1], acc);
        acc = fmaf(blo(pa.y), vcol[sel][2], acc);
        acc = fmaf(bhi(pa.y), vcol[sel][3], acc);
        acc = fmaf(blo(pb.x), vcol[sel][4], acc);
        acc = fmaf(bhi(pb.x), vcol[sel][5], acc);
        acc = fmaf(blo(pb.y), vcol[sel][6], acc);
        acc = fmaf(bhi(pb.y), vcol[sel][7], acc);
        acc = fmaf(blo(pc), vcol[sel][8], acc);
        acc = fmaf(bhi(pc), vcol[sel][9], acc);
        bufK[w + 4 * it][lane] = (__bf16)acc;
        rb += 4;
        if (rb >= 6) { rb -= 6; ++rq; }
      }
    }
    __syncthreads();

    // -------- proj (reads y in bufK) + residual --------
    {
      int4 b0 = ((const int4*)pf)[(0 * 4 + w) * 64 + lane];
      int4 b1 = ((const int4*)pf)[(1 * 4 + w) * 64 + lane];
#pragma unroll
      for (int mt = 0; mt < MT; ++mt) {
        int arow = mt * 16 + li16;
        int4 a0 = *(const int4*)&bufK[arow][lg * 8];
        int4 a1 = *(const int4*)&bufK[arow][32 + lg * 8];
        f32x4 acc = {0.f, 0.f, 0.f, 0.f};
        acc = mfma_bf16(a0, b0, acc);
        acc = mfma_bf16(a1, b1, acc);
#pragma unroll
        for (int r = 0; r < 4; ++r) h[mt][r] += acc[r];
      }
    }
    __syncthreads();

    ln_reg(&ln2_g[li * 64], &ln2_b[li * 64]);

    // -------- fused FFN: 2 chunk-pairs --------
    {
#pragma unroll
      for (int cp = 0; cp < 2; ++cp) {
#pragma unroll
        for (int cc = 0; cc < 2; ++cc) {
          int c = cp * 2 + cc;
          int nt1 = c * 4 + w;
          int4 b0 = ((const int4*)f1)[(0 * 16 + nt1) * 64 + lane];
          int4 b1 = ((const int4*)f1)[(1 * 16 + nt1) * 64 + lane];
          float bias1 = ffn_b1[li * 256 + c * 64 + col];
          __bf16(*gbuf)[APAD] = cc ? bufK : bufQ;
#pragma unroll
          for (int mt = 0; mt < MT; ++mt) {
            int arow = mt * 16 + li16;
            int4 a0 = *(const int4*)&actA[arow][lg * 8];
            int4 a1 = *(const int4*)&actA[arow][32 + lg * 8];
            f32x4 acc = {0.f, 0.f, 0.f, 0.f};
            acc = mfma_bf16(a0, b0, acc);
            acc = mfma_bf16(a1, b1, acc);
            if (mt < MT - 1 || lg < 3) {
#pragma unroll
              for (int r = 0; r < 4; ++r)
                gbuf[mt * 16 + lg * 4 + r][col] = (__bf16)gelu_f(acc[r] + bias1);
            }
          }
        }
        __syncthreads();
        f32x4 acc2[MT];
#pragma unroll
        for (int mt = 0; mt < MT; ++mt) acc2[mt] = {0.f, 0.f, 0.f, 0.f};
#pragma unroll
        for (int cc = 0; cc < 2; ++cc) {
          int c = cp * 2 + cc;
          int4 c0 = ((const int4*)f2)[((c * 2 + 0) * 4 + w) * 64 + lane];
          int4 c1 = ((const int4*)f2)[((c * 2 + 1) * 4 + w) * 64 + lane];
          __bf16(*gbuf)[APAD] = cc ? bufK : bufQ;
#pragma unroll
          for (int mt = 0; mt < MT; ++mt) {
            int arow = mt * 16 + li16;
            int4 a0 = *(const int4*)&gbuf[arow][lg * 8];
            int4 a1 = *(const int4*)&gbuf[arow][32 + lg * 8];
            acc2[mt] = mfma_bf16(a0, c0, acc2[mt]);
            acc2[mt] = mfma_bf16(a1, c1, acc2[mt]);
          }
        }
#pragma unroll
        for (int mt = 0; mt < MT; ++mt)
#pragma unroll
          for (int r = 0; r < 4; ++r) h[mt][r] += acc2[mt][r];
        __syncthreads();
      }
      float bias2 = ffn_b2[li * 64 + col];
#pragma unroll
      for (int mt = 0; mt < MT; ++mt)
#pragma unroll
        for (int r = 0; r < 4; ++r) h[mt][r] += bias2;
    }
  }

  // -------- final LN (rows 54..59 = t9) + head --------
  {
#pragma unroll
    for (int r = 0; r < 4; ++r) {
      int row = 48 + lg * 4 + r;
      if (row >= 54 && row < 60) hscr[row - 54][col] = h[3][r];
    }
  }
  __syncthreads();
  float2* sFin = (float2*)(lds_arena + SPR_OFF);
  if (tid < NB) {
    float s = 0.f, s2 = 0.f;
#pragma unroll
    for (int i = 0; i < 64; ++i) { float v = hscr[tid][i]; s += v; s2 = fmaf(v, v, s2); }
    float m = s * 0.015625f;
    sFin[tid] = make_float2(m, rsqrtf(s2 * 0.015625f - m * m + EPS));
  }
  __syncthreads();
  if (tid < NB * 10) {
    int b = (tid * 6554) >> 16;  // tid/10
    int j = tid - b * 10;
    int gb = blockIdx.x * NB + b;
    if (gb < 16384) {
      float m = sFin[b].x, rstd = sFin[b].y;
      float acc = head_b[j];
#pragma unroll
      for (int d = 0; d < 64; ++d) {
        float z = (hscr[b][d] - m) * rstd * lnf_g[d] + lnf_b[d];
        acc = fmaf(z, head_w[d * 10 + j], acc);
      }
      out[(size_t)gb * 10 + j] = acc;
    }
  }
}

}  // namespace

extern "C" void kernel_launch(void* const* d_in, const int* in_sizes, int n_in,
                              void* d_out, int out_size, void* d_ws, size_t ws_size,
                              hipStream_t stream) {
  const float* x       = (const float*)d_in[0];
  const float* embed_w = (const float*)d_in[1];
  const float* embed_b = (const float*)d_in[2];
  const float* ln1_g   = (const float*)d_in[3];
  const float* ln1_b   = (const float*)d_in[4];
  const float* qkv_w   = (const float*)d_in[5];
  const float* proj_w  = (const float*)d_in[6];
  const float* ln2_g   = (const float*)d_in[7];
  const float* ln2_b   = (const float*)d_in[8];
  const float* ffn_w1  = (const float*)d_in[9];
  const float* ffn_b1  = (const float*)d_in[10];
  const float* ffn_w2  = (const float*)d_in[11];
  const float* ffn_b2  = (const float*)d_in[12];
  const float* lnf_g   = (const float*)d_in[13];
  const float* lnf_b   = (const float*)d_in[14];
  const float* head_w  = (const float*)d_in[15];
  const float* head_b  = (const float*)d_in[16];
  __bf16* wf = (__bf16*)d_ws;
  float* out = (float*)d_out;

  prep_weights<<<dim3((WS_ELEMS + 255) / 256), dim3(256), 0, stream>>>(
      qkv_w, proj_w, ffn_w1, ffn_w2, wf);
  wtf_mfma<<<dim3(NBLK), dim3(256), 0, stream>>>(
      x, embed_w, embed_b, ln1_g, ln1_b, ln2_g, ln2_b, ffn_b1, ffn_b2,
      lnf_g, lnf_b, head_w, head_b, wf, out);
}

// Round 10
// 249.040 us; speedup vs baseline: 1.3227x; 1.0260x over previous
//
#include <hip/hip_runtime.h>

namespace {

typedef __bf16 bf16x8 __attribute__((ext_vector_type(8)));
typedef float f32x4 __attribute__((ext_vector_type(4)));

constexpr int NB = 6;          // batches per block
constexpr int ROWS = 60;       // NB * T   (row = t*6 + b)
constexpr int MT = 4;          // M-tiles of 16 (rows 60..63 are masked garbage)
constexpr int APAD = 72;       // bf16 staging row pitch (144 B, 16B-aligned)
constexpr int TPITCH = 62;     // V^T pitch (bf16; odd word stride -> conflict-free)
constexpr int HPAD = 67;       // hscr f32 pitch: odd word stride kills 16-row bank period
constexpr int PPITCH = 12;     // P row pitch in f32 (48 B, 16B-aligned rows)
constexpr int NBLK = (16384 + NB - 1) / NB;  // 2731
constexpr float EPS = 1e-5f;

// ws bf16-fragment offsets (elements)
constexpr int PROJF_OFF = 36864;
constexpr int F1F_OFF = 49152;
constexpr int F2F_OFF = 98304;
constexpr int WS_ELEMS = 147456;

// LDS arena offsets (bytes)
constexpr int ACT_OFF = 0;           // bf16[60][72] 8640 (aliased: bufT bf16[64][62]=7936)
constexpr int BUFQ_OFF = 8640;       // bf16[60][72] 8640 (hscr f32[64][67]=17152 spans Q+K)
constexpr int BUFK_OFF = 17280;      // bf16[60][72] 8640 (also y destination)
constexpr int SP_OFF = 25920;        // f32 P [240][12] = 11520 (alias: sXf/sPart/sGB/sFin)
constexpr int ARENA_BYTES = 37440;   // <= 40960 -> 4 blocks/CU (VGPR-capped anyway)

__device__ __forceinline__ uint pk2(float lo, float hi) {
  ushort ul = __builtin_bit_cast(ushort, (__bf16)lo);
  ushort uh = __builtin_bit_cast(ushort, (__bf16)hi);
  return (uint)ul | ((uint)uh << 16);
}
__device__ __forceinline__ float blo(uint u) { return __uint_as_float(u << 16); }
__device__ __forceinline__ float bhi(uint u) { return __uint_as_float(u & 0xffff0000u); }
__device__ __forceinline__ void unpack8(int4 v, float* f) {
  f[0] = blo(v.x); f[1] = bhi(v.x); f[2] = blo(v.y); f[3] = bhi(v.y);
  f[4] = blo(v.z); f[5] = bhi(v.z); f[6] = blo(v.w); f[7] = bhi(v.w);
}
// tanh-form gelu: 0.5v(1+tanh(.79788(v+.044715v^3))) = v - v/(e^{2z}+1)
__device__ __forceinline__ float gelu_f(float v) {
  float u = v * v;
  float arg = v * fmaf(u, 0.0713548162f, 1.5957691216f);  // 2z
  float r = __builtin_amdgcn_rcpf(__expf(arg) + 1.0f);
  return fmaf(-v, r, v);
}
__device__ __forceinline__ f32x4 mfma_bf16(int4 a, int4 b, f32x4 c) {
  return __builtin_amdgcn_mfma_f32_16x16x32_bf16(
      __builtin_bit_cast(bf16x8, a), __builtin_bit_cast(bf16x8, b), c, 0, 0, 0);
}

// ---------------- weight prep: fp32 row-major -> bf16 B-fragment layout ----
__global__ __launch_bounds__(256) void prep_weights(
    const float* __restrict__ qkv_w, const float* __restrict__ proj_w,
    const float* __restrict__ ffn_w1, const float* __restrict__ ffn_w2,
    __bf16* __restrict__ ws) {
  int idx = blockIdx.x * 256 + threadIdx.x;
  if (idx >= WS_ELEMS) return;
  const float* src;
  int N, Ksz, lstride, base;
  if (idx < PROJF_OFF) { src = qkv_w; N = 192; Ksz = 64; lstride = 12288; base = idx; }
  else if (idx < F1F_OFF) { src = proj_w; N = 64; Ksz = 64; lstride = 4096; base = idx - PROJF_OFF; }
  else if (idx < F2F_OFF) { src = ffn_w1; N = 256; Ksz = 64; lstride = 16384; base = idx - F1F_OFF; }
  else { src = ffn_w2; N = 64; Ksz = 256; lstride = 16384; base = idx - F2F_OFF; }
  int layer = base / lstride, rem = base % lstride;
  int ntk = N / 16;
  int kt = rem / (ntk * 512); rem %= (ntk * 512);
  int nt = rem / 512;
  int lane = (rem % 512) / 8, j = rem % 8;
  int k = kt * 32 + (lane >> 4) * 8 + j;
  int n = nt * 16 + (lane & 15);
  ws[idx] = (__bf16)src[(size_t)layer * Ksz * N + (size_t)k * N + n];
}

__global__ __launch_bounds__(256, 4) void wtf_mfma(
    const float* __restrict__ x, const float* __restrict__ embed_w,
    const float* __restrict__ embed_b, const float* __restrict__ ln1_g,
    const float* __restrict__ ln1_b, const float* __restrict__ ln2_g,
    const float* __restrict__ ln2_b, const float* __restrict__ ffn_b1,
    const float* __restrict__ ffn_b2, const float* __restrict__ lnf_g,
    const float* __restrict__ lnf_b, const float* __restrict__ head_w,
    const float* __restrict__ head_b, const __bf16* __restrict__ wf,
    float* __restrict__ out) {
  const int tid = threadIdx.x;
  const int lane = tid & 63;
  const int w = tid >> 6;
  const int li16 = lane & 15;
  const int lg = lane >> 4;
  const int col = w * 16 + li16;

  __shared__ __align__(16) char lds_arena[ARENA_BYTES];
  __bf16(*actA)[APAD] = (__bf16(*)[APAD])(lds_arena + ACT_OFF);
  __bf16(*bufQ)[APAD] = (__bf16(*)[APAD])(lds_arena + BUFQ_OFF);
  __bf16(*bufK)[APAD] = (__bf16(*)[APAD])(lds_arena + BUFK_OFF);
  __bf16* bufT        = (__bf16*)(lds_arena + ACT_OFF);        // V^T [64][62]
  float(*hscr)[HPAD]  = (float(*)[HPAD])(lds_arena + BUFQ_OFF);// f32[64][67] spans Q+K
  float* sP           = (float*)(lds_arena + SP_OFF);          // [bh*10+qt]*12 + kt
  float* sXf          = (float*)(lds_arena + SP_OFF);          // 240 f32 (embed only)
  float2(*sPart)[3]   = (float2(*)[3])(lds_arena + SP_OFF);    // 60x3 (LN only)
  float* sGB          = (float*)(lds_arena + SP_OFF + 2048);   // 128 f32 (LN only)

  f32x4 h[MT];  // residual: h[mt][r] = h(row=mt*16+lg*4+r, col); rows>=60 garbage

  auto ln_reg = [&](const float* g, const float* b) {
#pragma unroll
    for (int mt = 0; mt < MT; ++mt)
#pragma unroll
      for (int r = 0; r < 4; ++r) hscr[mt * 16 + lg * 4 + r][col] = h[mt][r];
    if (tid < 64) { sGB[tid] = g[tid]; sGB[64 + tid] = b[tid]; }
    __syncthreads();
    const int c3 = (tid >= 120) ? 2 : (tid >= 60 ? 1 : 0);
    const int row = tid - c3 * 60;
    const int beg = (c3 == 0) ? 0 : (c3 == 1) ? 22 : 44;
    const int len2 = (c3 < 2) ? 11 : 10;
    if (tid < 180) {
      float s = 0.f, s2 = 0.f;
      for (int k = 0; k < len2; ++k) {
        float vx = hscr[row][beg + 2 * k], vy = hscr[row][beg + 2 * k + 1];
        s += vx + vy;
        s2 = fmaf(vx, vx, fmaf(vy, vy, s2));
      }
      sPart[row][c3] = make_float2(s, s2);
    }
    __syncthreads();
    if (tid < 180) {
      float2 p0 = sPart[row][0], p1 = sPart[row][1], p2 = sPart[row][2];
      float s = p0.x + p1.x + p2.x, s2 = p0.y + p1.y + p2.y;
      float m = s * 0.015625f;
      float rstd = rsqrtf(s2 * 0.015625f - m * m + EPS);
      for (int k = 0; k < len2; ++k) {
        int c = beg + 2 * k;
        float vx = hscr[row][c], vy = hscr[row][c + 1];
        float v0 = (vx - m) * rstd * sGB[c] + sGB[64 + c];
        float v1 = (vy - m) * rstd * sGB[c + 1] + sGB[64 + c + 1];
        *(uint*)&actA[row][c] = pk2(v0, v1);
      }
    }
    __syncthreads();
  };

  // -------- stage x (240 f32) + embed into registers --------
  {
    int gx = blockIdx.x * (NB * 40) + tid;
    if (tid < NB * 40 && gx < 16384 * 40) sXf[tid] = x[gx];
  }
  __syncthreads();
  {
    float ew0 = embed_w[col], ew1 = embed_w[64 + col];
    float ew2 = embed_w[128 + col], ew3 = embed_w[192 + col];
    float eb = embed_b[col];
#pragma unroll
    for (int mt = 0; mt < MT; ++mt)
#pragma unroll
      for (int r = 0; r < 4; ++r) {
        int row = mt * 16 + lg * 4 + r;
        int t = (row * 43691) >> 18;          // row/6 (row<64)
        int b = row - t * 6;
        const float* xv = &sXf[b * 40 + t * 4];
        float acc = eb;
        acc = fmaf(xv[0], ew0, acc);
        acc = fmaf(xv[1], ew1, acc);
        acc = fmaf(xv[2], ew2, acc);
        acc = fmaf(xv[3], ew3, acc);
        h[mt][r] = acc;
      }
  }
  __syncthreads();

  for (int li = 0; li < 3; ++li) {
    const __bf16* qf = wf + li * 12288;
    const __bf16* pf = wf + PROJF_OFF + li * 4096;
    const __bf16* f1 = wf + F1F_OFF + li * 16384;
    const __bf16* f2 = wf + F2F_OFF + li * 16384;

    ln_reg(&ln1_g[li * 64], &ln1_b[li * 64]);

    // -------- fused QKV GEMM: Q->bufQ, K->bufK, V->regs --------
    uint2 vpk[MT];
    {
      int4 bq[3][2];
#pragma unroll
      for (int ii = 0; ii < 3; ++ii)
#pragma unroll
        for (int kt = 0; kt < 2; ++kt)
          bq[ii][kt] = ((const int4*)qf)[(kt * 12 + (w + 4 * ii)) * 64 + lane];
#pragma unroll
      for (int mt = 0; mt < MT; ++mt) {
        int arow = mt * 16 + li16;
        int4 a0 = *(const int4*)&actA[arow][lg * 8];
        int4 a1 = *(const int4*)&actA[arow][32 + lg * 8];
        f32x4 aq = {0.f, 0.f, 0.f, 0.f};
        aq = mfma_bf16(a0, bq[0][0], aq);
        aq = mfma_bf16(a1, bq[0][1], aq);
        f32x4 ak = {0.f, 0.f, 0.f, 0.f};
        ak = mfma_bf16(a0, bq[1][0], ak);
        ak = mfma_bf16(a1, bq[1][1], ak);
        f32x4 av = {0.f, 0.f, 0.f, 0.f};
        av = mfma_bf16(a0, bq[2][0], av);
        av = mfma_bf16(a1, bq[2][1], av);
        if (mt < MT - 1 || lg < 3) {  // rows < 60
#pragma unroll
          for (int r = 0; r < 4; ++r) bufQ[mt * 16 + lg * 4 + r][col] = (__bf16)aq[r];
#pragma unroll
          for (int r = 0; r < 4; ++r) bufK[mt * 16 + lg * 4 + r][col] = (__bf16)ak[r];
        }
        vpk[mt].x = pk2(av[0], av[1]);
        vpk[mt].y = pk2(av[2], av[3]);
      }
    }
    __syncthreads();

    // -------- V^T write FIRST (vpk dies early), then scores+softmax --------
    {
      const int coff = col * TPITCH;
#pragma unroll
      for (int mt = 0; mt < MT; ++mt) {
        if (mt < MT - 1 || lg < 3) {
          uint* dst = (uint*)&bufT[coff + mt * 16 + lg * 4];
          dst[0] = vpk[mt].x;
          dst[1] = vpk[mt].y;
        }
      }
      if (tid < 240) {
        int qt = (tid * 43691) >> 20;  // tid/24
        int bh = tid - qt * 24;
        int b = bh >> 2, hh = bh & 3;
        int qrow = qt * 6 + b;
        float qv[16];
        {
          int4 qa = *(const int4*)&bufQ[qrow][hh * 16];
          int4 qb = *(const int4*)&bufQ[qrow][hh * 16 + 8];
          unpack8(qa, qv); unpack8(qb, qv + 8);
        }
        float sc[10], mx = -1e30f;
#pragma unroll
        for (int kt = 0; kt < 10; ++kt) {
          int4 ka = *(const int4*)&bufK[kt * 6 + b][hh * 16];
          int4 kb = *(const int4*)&bufK[kt * 6 + b][hh * 16 + 8];
          float kv[16]; unpack8(ka, kv); unpack8(kb, kv + 8);
          float d = 0.f;
#pragma unroll
          for (int i = 0; i < 16; ++i) d = fmaf(qv[i], kv[i], d);
          sc[kt] = (kt <= qt) ? d * 0.25f : -1e30f;
          mx = fmaxf(mx, sc[kt]);
        }
        float ssum = 0.f;
#pragma unroll
        for (int kt = 0; kt < 10; ++kt) { sc[kt] = __expf(sc[kt] - mx); ssum += sc[kt]; }
        float inv = __builtin_amdgcn_rcpf(ssum);
        float* prow = &sP[(bh * 10 + qt) * PPITCH];
#pragma unroll
        for (int i = 0; i < 5; ++i)
          *(float2*)&prow[2 * i] = make_float2(sc[2 * i] * inv, sc[2 * i + 1] * inv);
      }
    }
    __syncthreads();

    // -------- AV: y = P @ V -> bufK; 3 groups of 5 rows, one vcol set live ----
    {
      const int hh = lane >> 4;
#pragma unroll
      for (int g = 0; g < 3; ++g) {
        const int bg = (w + 4 * g) % 6;
        const int r0 = w + 4 * g;         // < 12
        const int qt0 = (r0 >= 6) ? 1 : 0;
        float vcol[10];
#pragma unroll
        for (int kt = 0; kt < 10; ++kt)
          vcol[kt] = (float)bufT[lane * TPITCH + kt * 6 + bg];
#pragma unroll
        for (int j = 0; j < 5; ++j) {
          const int r = r0 + 12 * j;
          const int qt = qt0 + 2 * j;
          const float* prow = &sP[((bg * 4 + hh) * 10 + qt) * PPITCH];
          float4 pa = *(const float4*)&prow[0];
          float4 pb = *(const float4*)&prow[4];
          float2 pc = *(const float2*)&prow[8];
          float acc = 0.f;
          acc = fmaf(pa.x, vcol[0], acc);
          acc = fmaf(pa.y, vcol[1], acc);
          acc = fmaf(pa.z, vcol[2], acc);
          acc = fmaf(pa.w, vcol[3], acc);
          acc = fmaf(pb.x, vcol[4], acc);
          acc = fmaf(pb.y, vcol[5], acc);
          acc = fmaf(pb.z, vcol[6], acc);
          acc = fmaf(pb.w, vcol[7], acc);
          acc = fmaf(pc.x, vcol[8], acc);
          acc = fmaf(pc.y, vcol[9], acc);
          bufK[r][lane] = (__bf16)acc;
        }
      }
    }
    __syncthreads();

    // -------- proj (reads y in bufK) + residual --------
    {
      int4 b0 = ((const int4*)pf)[(0 * 4 + w) * 64 + lane];
      int4 b1 = ((const int4*)pf)[(1 * 4 + w) * 64 + lane];
#pragma unroll
      for (int mt = 0; mt < MT; ++mt) {
        int arow = mt * 16 + li16;
        int4 a0 = *(const int4*)&bufK[arow][lg * 8];
        int4 a1 = *(const int4*)&bufK[arow][32 + lg * 8];
        f32x4 acc = {0.f, 0.f, 0.f, 0.f};
        acc = mfma_bf16(a0, b0, acc);
        acc = mfma_bf16(a1, b1, acc);
#pragma unroll
        for (int r = 0; r < 4; ++r) h[mt][r] += acc[r];
      }
    }
    __syncthreads();

    ln_reg(&ln2_g[li * 64], &ln2_b[li * 64]);

    // -------- fused FFN: 2 chunk-pairs --------
    {
#pragma unroll
      for (int cp = 0; cp < 2; ++cp) {
#pragma unroll
        for (int cc = 0; cc < 2; ++cc) {
          int c = cp * 2 + cc;
          int nt1 = c * 4 + w;
          int4 b0 = ((const int4*)f1)[(0 * 16 + nt1) * 64 + lane];
          int4 b1 = ((const int4*)f1)[(1 * 16 + nt1) * 64 + lane];
          float bias1 = ffn_b1[li * 256 + c * 64 + col];
          __bf16(*gbuf)[APAD] = cc ? bufK : bufQ;
#pragma unroll
          for (int mt = 0; mt < MT; ++mt) {
            int arow = mt * 16 + li16;
            int4 a0 = *(const int4*)&actA[arow][lg * 8];
            int4 a1 = *(const int4*)&actA[arow][32 + lg * 8];
            f32x4 acc = {0.f, 0.f, 0.f, 0.f};
            acc = mfma_bf16(a0, b0, acc);
            acc = mfma_bf16(a1, b1, acc);
            if (mt < MT - 1 || lg < 3) {
#pragma unroll
              for (int r = 0; r < 4; ++r)
                gbuf[mt * 16 + lg * 4 + r][col] = (__bf16)gelu_f(acc[r] + bias1);
            }
          }
        }
        __syncthreads();
        f32x4 acc2[MT];
#pragma unroll
        for (int mt = 0; mt < MT; ++mt) acc2[mt] = {0.f, 0.f, 0.f, 0.f};
#pragma unroll
        for (int cc = 0; cc < 2; ++cc) {
          int c = cp * 2 + cc;
          int4 c0 = ((const int4*)f2)[((c * 2 + 0) * 4 + w) * 64 + lane];
          int4 c1 = ((const int4*)f2)[((c * 2 + 1) * 4 + w) * 64 + lane];
          __bf16(*gbuf)[APAD] = cc ? bufK : bufQ;
#pragma unroll
          for (int mt = 0; mt < MT; ++mt) {
            int arow = mt * 16 + li16;
            int4 a0 = *(const int4*)&gbuf[arow][lg * 8];
            int4 a1 = *(const int4*)&gbuf[arow][32 + lg * 8];
            acc2[mt] = mfma_bf16(a0, c0, acc2[mt]);
            acc2[mt] = mfma_bf16(a1, c1, acc2[mt]);
          }
        }
#pragma unroll
        for (int mt = 0; mt < MT; ++mt)
#pragma unroll
          for (int r = 0; r < 4; ++r) h[mt][r] += acc2[mt][r];
        __syncthreads();
      }
      float bias2 = ffn_b2[li * 64 + col];
#pragma unroll
      for (int mt = 0; mt < MT; ++mt)
#pragma unroll
        for (int r = 0; r < 4; ++r) h[mt][r] += bias2;
    }
  }

  // -------- final LN (rows 54..59 = t9) + head --------
  {
#pragma unroll
    for (int r = 0; r < 4; ++r) {
      int row = 48 + lg * 4 + r;
      if (row >= 54 && row < 60) hscr[row - 54][col] = h[3][r];
    }
  }
  __syncthreads();
  float2* sFin = (float2*)(lds_arena + SP_OFF);
  if (tid < NB) {
    float s = 0.f, s2 = 0.f;
#pragma unroll
    for (int i = 0; i < 64; ++i) { float v = hscr[tid][i]; s += v; s2 = fmaf(v, v, s2); }
    float m = s * 0.015625f;
    sFin[tid] = make_float2(m, rsqrtf(s2 * 0.015625f - m * m + EPS));
  }
  __syncthreads();
  if (tid < NB * 10) {
    int b = (tid * 6554) >> 16;  // tid/10
    int j = tid - b * 10;
    int gb = blockIdx.x * NB + b;
    if (gb < 16384) {
      float m = sFin[b].x, rstd = sFin[b].y;
      float acc = head_b[j];
#pragma unroll
      for (int d = 0; d < 64; ++d) {
        float z = (hscr[b][d] - m) * rstd * lnf_g[d] + lnf_b[d];
        acc = fmaf(z, head_w[d * 10 + j], acc);
      }
      out[(size_t)gb * 10 + j] = acc;
    }
  }
}

}  // namespace

extern "C" void kernel_launch(void* const* d_in, const int* in_sizes, int n_in,
                              void* d_out, int out_size, void* d_ws, size_t ws_size,
                              hipStream_t stream) {
  const float* x       = (const float*)d_in[0];
  const float* embed_w = (const float*)d_in[1];
  const float* embed_b = (const float*)d_in[2];
  const float* ln1_g   = (const float*)d_in[3];
  const float* ln1_b   = (const float*)d_in[4];
  const float* qkv_w   = (const float*)d_in[5];
  const float* proj_w  = (const float*)d_in[6];
  const float* ln2_g   = (const float*)d_in[7];
  const float* ln2_b   = (const float*)d_in[8];
  const float* ffn_w1  = (const float*)d_in[9];
  const float* ffn_b1  = (const float*)d_in[10];
  const float* ffn_w2  = (const float*)d_in[11];
  const float* ffn_b2  = (const float*)d_in[12];
  const float* lnf_g   = (const float*)d_in[13];
  const float* lnf_b   = (const float*)d_in[14];
  const float* head_w  = (const float*)d_in[15];
  const float* head_b  = (const float*)d_in[16];
  __bf16* wf = (__bf16*)d_ws;
  float* out = (float*)d_out;

  prep_weights<<<dim3((WS_ELEMS + 255) / 256), dim3(256), 0, stream>>>(
      qkv_w, proj_w, ffn_w1, ffn_w2, wf);
  wtf_mfma<<<dim3(NBLK), dim3(256), 0, stream>>>(
      x, embed_w, embed_b, ln1_g, ln1_b, ln2_g, ln2_b, ffn_b1, ffn_b2,
      lnf_g, lnf_b, head_w, head_b, wf, out);
}